// Round 6
// baseline (47.114 us; speedup 1.0000x reference)
//
#include <hip/hip_runtime.h>
#include <hip/hip_bf16.h>
#include <math.h>

// ImplicitPolygonInjector: B=4, C=128, H=W=64, S=4
// out[b][j][h*4+sy][w*4+sx] = (relu(hf[b,h,w,:]+hg[sy,sx,:]+b1) @ w2 + b2)[j] * gate[b,h,w]
//
// R5: R4 + fix: phase-A hf_s row is (gm>>2)&15 (w), not gm>>2 (= sy*16+w, OOB for sy>=1).
// Steady state = 8 chunks of 32 m-rows, double-buffered hid (2x8KB). Each barrier
// interval = {phase A(c+1) || phase B(c)}: stores+MFMA+LDS mix in every interval.
// lgkm-only barriers; no global loads in loop -> output stores never drained.

typedef __attribute__((ext_vector_type(8))) short bf16x8;
typedef __attribute__((ext_vector_type(4))) float f32x4;

__device__ inline short f2bf(float v) {
    __hip_bfloat16 b = __float2bfloat16(v);
    return *reinterpret_cast<short*>(&b);
}

__device__ inline void barrier_lgkm() {
    asm volatile("s_waitcnt lgkmcnt(0)" ::: "memory");
    __builtin_amdgcn_s_barrier();
    asm volatile("" ::: "memory");
}

// ---------------- pre-kernel: transposes + bf16 hi/lo split ----------------
__global__ __launch_bounds__(256) void ipi_pre_kernel(
    const float* __restrict__ w2,    // (128,128)
    const float* __restrict__ w1,    // (130,128) -- rows 0..127 used
    const float* __restrict__ gw1,   // (128,32)
    __hip_bfloat16* __restrict__ w2t,     // (128j,128k)
    __hip_bfloat16* __restrict__ w1t_hi,  // (128j,128c)
    __hip_bfloat16* __restrict__ w1t_lo,
    __hip_bfloat16* __restrict__ g1t_hi,  // (32jg,128c)
    __hip_bfloat16* __restrict__ g1t_lo)
{
    int gid = blockIdx.x * 256 + threadIdx.x;
    if (gid < 16384) {
        int j = gid >> 7, k = gid & 127;
        w2t[gid] = __float2bfloat16(w2[k * 128 + j]);
    } else if (gid < 32768) {
        int i = gid - 16384, j = i >> 7, c = i & 127;
        float v = w1[c * 128 + j];
        __hip_bfloat16 hi = __float2bfloat16(v);
        w1t_hi[i] = hi;
        w1t_lo[i] = __float2bfloat16(v - __bfloat162float(hi));
    } else if (gid < 36864) {
        int i = gid - 32768, jg = i >> 7, c = i & 127;
        float v = gw1[c * 32 + jg];
        __hip_bfloat16 hi = __float2bfloat16(v);
        g1t_hi[i] = hi;
        g1t_lo[i] = __float2bfloat16(v - __bfloat162float(hi));
    }
}

// ---------------- main kernel ----------------
__global__ __launch_bounds__(256, 4) void ipi_main(
    const float* __restrict__ feat,     // (4,128,64,64)
    const float* __restrict__ mlp_w1,   // (130,128) -- rows 128,129 (grid coords)
    const float* __restrict__ mlp_b1,   // (128,)
    const float* __restrict__ gate_w2,  // (32,)
    const float* __restrict__ gate_b2,  // (1,)
    const float* __restrict__ mlp_b2,   // (128,)
    const __hip_bfloat16* __restrict__ w2t,
    const __hip_bfloat16* __restrict__ w1t_hi,
    const __hip_bfloat16* __restrict__ w1t_lo,
    const __hip_bfloat16* __restrict__ g1t_hi,
    const __hip_bfloat16* __restrict__ g1t_lo,
    float* __restrict__ out)            // (4,128,256,256)
{
    __shared__ float hf_s[16 * 132];    // hf[w][k] fp32
    __shared__ float hgb_s[16 * 132];   // hgb[s][k] fp32
    __shared__ float gate_s[16];
    __shared__ char  hid[16384];        // 2 x 8KB: bf16 [32 m][128 k] swizzled
    short* f_hi = (short*)hid;          // [16 w][136 c]  (prologue only, 0..4352)
    short* f_lo = (short*)(hid + 4352); //                (4352..8704)
    float* glds = (float*)(hid + 8704); // [16 w][33 jg]  (8704..10816, dead after sigmoid)

    const int t    = threadIdx.x;
    const int lane = t & 63;
    const int lg   = lane >> 4;         // 0..3
    const int ml   = lane & 15;
    const int wv   = t >> 6;            // wave id -> j-range wv*32..+31
    const int bx   = blockIdx.x;
    const int w0   = (bx & 3) * 16;
    const int h    = (bx >> 2) & 63;
    const int b    = bx >> 8;

    // ---- w2t A-frags + b2 (C-operand init values) ----
    bf16x8 afrag[2][4];
    f32x4  b2v[2];
    {
        const __hip_bfloat16* base = w2t + (wv * 32 + ml) * 128 + lg * 8;
        #pragma unroll
        for (int jt = 0; jt < 2; ++jt) {
            #pragma unroll
            for (int ks = 0; ks < 4; ++ks)
                afrag[jt][ks] = *(const bf16x8*)(base + jt * 2048 + ks * 32);
            b2v[jt] = *(const f32x4*)&mlp_b2[wv * 32 + jt * 16 + lg * 4];
        }
    }

    // ---- 8 store pointers: [jt*4+r] -> row j = wv*32+jt*16+lg*4+r, sy=0, col base ----
    float* ptrs[8];
    {
        float* pbase = out + ((size_t)(b * 128 + wv * 32 + lg * 4) << 16)
                           + (size_t)(h * 4) * 256 + w0 * 4 + ml;
        #pragma unroll
        for (int jt = 0; jt < 2; ++jt)
            #pragma unroll
            for (int r = 0; r < 4; ++r)
                ptrs[jt * 4 + r] = pbase + ((size_t)(jt * 16 + r) << 16);
    }

    // ---- stage f (transposed, bf16 hi/lo) + hgb ----
    {
        const float* fbase = feat + ((size_t)(b * 128) * 64 + h) * 64 + w0;
        #pragma unroll
        for (int i = 0; i < 8; ++i) {
            int idx = t + i * 256;            // 2048 = 128c * 16w
            int c = idx >> 4, w = idx & 15;
            float v = fbase[(size_t)c * 4096 + w];
            short hi = f2bf(v);
            float hf32 = __bfloat162float(*(__hip_bfloat16*)&hi);
            f_hi[w * 136 + c] = hi;
            f_lo[w * 136 + c] = f2bf(v - hf32);
        }
        #pragma unroll
        for (int i = 0; i < 8; ++i) {
            int idx = t + i * 256;            // 2048 = 16s * 128k
            int s = idx >> 7, k = idx & 127;
            float cx = -0.75f + 0.5f * (float)(s & 3);
            float cy = -0.75f + 0.5f * (float)(s >> 2);
            hgb_s[s * 132 + k] = cx * mlp_w1[16384 + k]
                               + cy * mlp_w1[16512 + k] + mlp_b1[k];
        }
    }
    barrier_lgkm();

    // ---- hf = f @ w1_f via split-bf16 MFMA (all waves); gate MFMA (wave 0) ----
    {
        bf16x8 fhi[4], flo[4];
        {
            const short* fb  = f_hi + ml * 136 + lg * 8;
            const short* flb = f_lo + ml * 136 + lg * 8;
            #pragma unroll
            for (int ks = 0; ks < 4; ++ks) {
                fhi[ks] = *(const bf16x8*)(fb + ks * 32);
                flo[ks] = *(const bf16x8*)(flb + ks * 32);
            }
        }
        #pragma unroll
        for (int jj = 0; jj < 2; ++jj) {
            const int jt16 = (wv * 2 + jj) * 16;
            const __hip_bfloat16* bh = w1t_hi + (jt16 + ml) * 128 + lg * 8;
            const __hip_bfloat16* bl = w1t_lo + (jt16 + ml) * 128 + lg * 8;
            f32x4 acc = {0.f, 0.f, 0.f, 0.f};
            #pragma unroll
            for (int ks = 0; ks < 4; ++ks) {
                bf16x8 Bh = *(const bf16x8*)(bh + ks * 32);
                bf16x8 Bl = *(const bf16x8*)(bl + ks * 32);
                acc = __builtin_amdgcn_mfma_f32_16x16x32_bf16(fhi[ks], Bh, acc, 0, 0, 0);
                acc = __builtin_amdgcn_mfma_f32_16x16x32_bf16(fhi[ks], Bl, acc, 0, 0, 0);
                acc = __builtin_amdgcn_mfma_f32_16x16x32_bf16(flo[ks], Bh, acc, 0, 0, 0);
            }
            #pragma unroll
            for (int r = 0; r < 4; ++r)
                hf_s[(lg * 4 + r) * 132 + jt16 + ml] = acc[r];
        }
        if (wv == 0) {
            #pragma unroll
            for (int jt = 0; jt < 2; ++jt) {
                const __hip_bfloat16* bh = g1t_hi + (jt * 16 + ml) * 128 + lg * 8;
                const __hip_bfloat16* bl = g1t_lo + (jt * 16 + ml) * 128 + lg * 8;
                f32x4 acc = {0.f, 0.f, 0.f, 0.f};
                #pragma unroll
                for (int ks = 0; ks < 4; ++ks) {
                    bf16x8 Bh = *(const bf16x8*)(bh + ks * 32);
                    bf16x8 Bl = *(const bf16x8*)(bl + ks * 32);
                    acc = __builtin_amdgcn_mfma_f32_16x16x32_bf16(fhi[ks], Bh, acc, 0, 0, 0);
                    acc = __builtin_amdgcn_mfma_f32_16x16x32_bf16(fhi[ks], Bl, acc, 0, 0, 0);
                    acc = __builtin_amdgcn_mfma_f32_16x16x32_bf16(flo[ks], Bh, acc, 0, 0, 0);
                }
                #pragma unroll
                for (int r = 0; r < 4; ++r) {
                    float v = acc[r];
                    glds[(lg * 4 + r) * 33 + jt * 16 + ml] = (v >= 0.f) ? v : 0.2f * v;
                }
            }
        }
    }
    barrier_lgkm();

    // ---- phase A lambda: chunk c -> hid[buf c&1], rows m = c*32 + (t&31) ----
    const int am = t & 31;              // row within chunk
    const int ak = t >> 5;              // k16 chunk 0..7 (16 k each)
    const int asw = (am & 7) << 4;
    auto phaseA = [&](int c) {
        const int gm = c * 32 + am;                   // global m row (0..255)
        const float* hfr = hf_s  + ((gm >> 2) & 15) * 132 + ak * 16;   // w row (FIXED)
        const float* hgr = hgb_s + (((gm >> 6) << 2) | (gm & 3)) * 132 + ak * 16;
        char* wp = hid + (c & 1) * 8192 + am * 256;
        float4 a0 = *(const float4*)(hfr);
        float4 a1 = *(const float4*)(hfr + 4);
        float4 a2 = *(const float4*)(hfr + 8);
        float4 a3 = *(const float4*)(hfr + 12);
        float4 g0 = *(const float4*)(hgr);
        float4 g1 = *(const float4*)(hgr + 4);
        float4 g2 = *(const float4*)(hgr + 8);
        float4 g3 = *(const float4*)(hgr + 12);
        bf16x8 hv0, hv1;
        hv0[0] = f2bf(fmaxf(a0.x + g0.x, 0.f));
        hv0[1] = f2bf(fmaxf(a0.y + g0.y, 0.f));
        hv0[2] = f2bf(fmaxf(a0.z + g0.z, 0.f));
        hv0[3] = f2bf(fmaxf(a0.w + g0.w, 0.f));
        hv0[4] = f2bf(fmaxf(a1.x + g1.x, 0.f));
        hv0[5] = f2bf(fmaxf(a1.y + g1.y, 0.f));
        hv0[6] = f2bf(fmaxf(a1.z + g1.z, 0.f));
        hv0[7] = f2bf(fmaxf(a1.w + g1.w, 0.f));
        hv1[0] = f2bf(fmaxf(a2.x + g2.x, 0.f));
        hv1[1] = f2bf(fmaxf(a2.y + g2.y, 0.f));
        hv1[2] = f2bf(fmaxf(a2.z + g2.z, 0.f));
        hv1[3] = f2bf(fmaxf(a2.w + g2.w, 0.f));
        hv1[4] = f2bf(fmaxf(a3.x + g3.x, 0.f));
        hv1[5] = f2bf(fmaxf(a3.y + g3.y, 0.f));
        hv1[6] = f2bf(fmaxf(a3.z + g3.z, 0.f));
        hv1[7] = f2bf(fmaxf(a3.w + g3.w, 0.f));
        *(bf16x8*)(wp + ((ak * 32) ^ asw))      = hv0;
        *(bf16x8*)(wp + ((ak * 32 + 16) ^ asw)) = hv1;
    };

    // ---- interval: gate sigmoid || phase A(0) ----
    if (t < 16) {
        float s = gate_b2[0];
        #pragma unroll 8
        for (int jg = 0; jg < 32; ++jg) s = fmaf(glds[t * 33 + jg], gate_w2[jg], s);
        gate_s[t] = 1.f / (1.f + expf(-s));
    }
    phaseA(0);
    barrier_lgkm();

    // ---- steady state: 8 chunks; interval = { A(c+1) || B(c) }; lgkm barriers ----
    #pragma unroll
    for (int c = 0; c < 8; ++c) {
        if (c < 7) phaseA(c + 1);

        const char* buf = hid + (c & 1) * 8192;
        #pragma unroll
        for (int mt = 0; mt < 2; ++mt) {
            const int row = mt * 16 + ml;
            const int swb = (row & 7) << 4;
            const char* rp = buf + row * 256;
            bf16x8 bfrag[4];
            #pragma unroll
            for (int ks = 0; ks < 4; ++ks)
                bfrag[ks] = *(const bf16x8*)(rp + ((ks * 64 + lg * 16) ^ swb));

            f32x4 acc0 = b2v[0];
            f32x4 acc1 = b2v[1];
            #pragma unroll
            for (int ks = 0; ks < 4; ++ks) {
                acc0 = __builtin_amdgcn_mfma_f32_16x16x32_bf16(afrag[0][ks], bfrag[ks], acc0, 0, 0, 0);
                acc1 = __builtin_amdgcn_mfma_f32_16x16x32_bf16(afrag[1][ks], bfrag[ks], acc1, 0, 0, 0);
            }

            const float g = gate_s[((c & 1) << 3) + (row >> 2)];
            const int off = (c >> 1) * 256 + (c & 1) * 32 + mt * 16;  // compile-time
            #pragma unroll
            for (int r = 0; r < 4; ++r) {
                ptrs[r][off]     = acc0[r] * g;
                ptrs[4 + r][off] = acc1[r] * g;
            }
        }
        barrier_lgkm();
    }
}

extern "C" void kernel_launch(void* const* d_in, const int* in_sizes, int n_in,
                              void* d_out, int out_size, void* d_ws, size_t ws_size,
                              hipStream_t stream) {
    const float* feat = (const float*)d_in[0];
    const float* gw1  = (const float*)d_in[1];
    const float* gw2  = (const float*)d_in[2];
    const float* gb2  = (const float*)d_in[3];
    const float* w1   = (const float*)d_in[4];
    const float* b1   = (const float*)d_in[5];
    const float* w2   = (const float*)d_in[6];
    const float* b2   = (const float*)d_in[7];
    float* o = (float*)d_out;

    // ws: w2t 32K | w1t_hi 32K | w1t_lo 32K | g1t_hi 8K | g1t_lo 8K = 112K
    char* ws = (char*)d_ws;
    __hip_bfloat16* w2t    = (__hip_bfloat16*)(ws);
    __hip_bfloat16* w1t_hi = (__hip_bfloat16*)(ws + 32768);
    __hip_bfloat16* w1t_lo = (__hip_bfloat16*)(ws + 65536);
    __hip_bfloat16* g1t_hi = (__hip_bfloat16*)(ws + 98304);
    __hip_bfloat16* g1t_lo = (__hip_bfloat16*)(ws + 106496);

    ipi_pre_kernel<<<dim3(144), dim3(256), 0, stream>>>(
        w2, w1, gw1, w2t, w1t_hi, w1t_lo, g1t_hi, g1t_lo);
    ipi_main<<<dim3(1024), dim3(256), 0, stream>>>(
        feat, w1, b1, gw2, gb2, b2, w2t, w1t_hi, w1t_lo, g1t_hi, g1t_lo, o);
}